// Round 6
// baseline (794.684 us; speedup 1.0000x reference)
//
#include <hip/hip_runtime.h>

#define T_ 512
#define K_ 128
#define B_ 256
#define NEGINF (-3.4028235e38f)

// LDS-only barrier: __syncthreads() drains vmcnt(0) before s_barrier, which
// serializes any in-flight global load into the per-step critical path
// (rounds 1-5: invariant ~2725 cyc/step regardless of structure). The
// recurrence only needs LDS visibility -> wait lgkmcnt only.
#define BAR() do { asm volatile("s_waitcnt lgkmcnt(0)" ::: "memory"); \
                   __builtin_amdgcn_s_barrier(); \
                   asm volatile("" ::: "memory"); } while (0)

#define GR16(F) F(0) F(1) F(2) F(3) F(4) F(5) F(6) F(7) \
                F(8) F(9) F(10) F(11) F(12) F(13) F(14) F(15)

#define DECLW(g) float w##g##_0, w##g##_1, w##g##_2, w##g##_3;
#define LOADW(g) w##g##_0 = wp[(4*g+0)*K_]; w##g##_1 = wp[(4*g+1)*K_]; \
                 w##g##_2 = wp[(4*g+2)*K_]; w##g##_3 = wp[(4*g+3)*K_];
#define EXPW(g)  w##g##_0 = __expf(w##g##_0); w##g##_1 = __expf(w##g##_1); \
                 w##g##_2 = __expf(w##g##_2); w##g##_3 = __expf(w##g##_3);
#define FENCEW(g) asm volatile("" : "+v"(w##g##_0), "+v"(w##g##_1), \
                                    "+v"(w##g##_2), "+v"(w##g##_3));

// fwd dot: group g -> accumulator g&3 (4 independent chains)
#define FG(g, acc) { float4 e_ = *(const float4*)(va + 4*g); \
    acc = fmaf(e_.x, w##g##_0, acc); acc = fmaf(e_.y, w##g##_1, acc); \
    acc = fmaf(e_.z, w##g##_2, acc); acc = fmaf(e_.w, w##g##_3, acc); }

// vit max/arg: ascending idx + strict > = first-max-wins
#define VG(g, mm, aa) { float4 e_ = *(const float4*)(va + 4*g); \
    float s0_ = e_.x + w##g##_0; if (s0_ > mm) { mm = s0_; aa = 4*g+0; } \
    float s1_ = e_.y + w##g##_1; if (s1_ > mm) { mm = s1_; aa = 4*g+1; } \
    float s2_ = e_.z + w##g##_2; if (s2_ > mm) { mm = s2_; aa = 4*g+2; } \
    float s3_ = e_.w + w##g##_3; if (s3_ > mm) { mm = s3_; aa = 4*g+3; } }

// 512 blocks x 256 threads (4 waves). role = blockIdx&1 (0=forward, 1=viterbi).
// Lane: j = tid>>1 (column), c = tid&1 (i-half). W[c*64..+63][j] in 64 named
// registers (asm fence). One barrier/step; pair merge via shfl_xor(1) in-wave.
// Emissions staged in LDS by 8-step chunks, double buffered: global load issued
// at step phase 1, ds_write at phase 6, consumed next chunk -> VMEM latency
// never enters the step chain (BAR never waits vmcnt).
__global__ __launch_bounds__(256, 2) void crf_main(
    const float* __restrict__ emissions,
    const int* __restrict__ tag_ids,
    const int* __restrict__ lengths,
    const float* __restrict__ transitions,
    float* __restrict__ out,
    float* __restrict__ ws_ll,
    int* __restrict__ ws_cnt)
{
    __shared__ __align__(16) unsigned char smem[75328];
    unsigned char* bp  = smem;                        // [T_*K_]    (vit)
    float* emLDS = (float*)(smem + 65536);            // [2][8*128] staged emissions
    float* buf   = (float*)(smem + 73728);            // [2][128]   alpha-exp / viterbi
    unsigned char* dec = smem + 74752;                // [T_]
    float* sNormF = (float*)(smem + 75264);           // [2]
    float* redS   = sNormF + 2;                       // [4]
    int*   redI   = (int*)(redS + 4);                 // [4]
    int*   ltag   = redI + 4;                         // [1]

    const int bx   = blockIdx.x;
    const int b    = bx >> 1;
    const int role = bx & 1;
    const int tid  = threadIdx.x;
    const int len  = lengths[b];
    const float* emB = emissions + (size_t)b * T_ * K_;
    const int*  tagB = tag_ids + b * T_;

    const int j = tid >> 1;             // column 0..127
    const int c = tid & 1;              // i-half

    GR16(DECLW)
    {
        const float* wp = transitions + (c * 64) * K_ + j;
        GR16(LOADW)
        if (role == 0) { GR16(EXPW) }
        GR16(FENCEW)
    }

    // ---------------- init: stage chunk 0, init state, seq-score ----------------
    {   // chunk 0 (t=0..7) -> slot 0 : one float4 per thread
        float4 v0 = *(const float4*)&emB[tid * 4];
        *(float4*)&emLDS[tid * 4] = v0;
    }
    if (role == 0) {
        float s = 0.f;
        #pragma unroll
        for (int q = 0; q < 2; ++q) {
            int t = tid + q * 256;
            if (t < len) {
                int tg = tagB[t];
                float v = emB[t * K_ + tg];
                if (t >= 1) v += transitions[tagB[t - 1] * K_ + tg];
                s += v;
            }
        }
        #pragma unroll
        for (int m = 1; m < 64; m <<= 1) s += __shfl_xor(s, m);
        if ((tid & 63) == 0) redS[tid >> 6] = s;
        if (tid < K_) buf[tid] = __expf(emB[tid]);    // offset S = 0
        if (tid == 0) sNormF[0] = emB[0];
    } else {
        if (tid < K_) buf[tid] = emB[tid];
    }
    __syncthreads();                                  // init has global deps: full sync once

    // ---------------- main recurrence: ONE lgkm-barrier per step ----------------
    int cur = 0;
    float Sprev = 0.f;                                // offset of buf[cur] (fwd)
    float4 stv = make_float4(0.f, 0.f, 0.f, 0.f);     // staged chunk in flight
    for (int t = 1; t < len; ++t) {
        const int ph = t & 7;
        if (ph == 1) {                                // issue next-chunk load early
            int nc = (t >> 3) + 1;
            if (nc < T_ / 8) {
                stv = *(const float4*)&emB[nc * 1024 + tid * 4];
                asm volatile("" : "+v"(stv.x), "+v"(stv.y), "+v"(stv.z), "+v"(stv.w));
            }
        }
        const float* va = &buf[cur * K_ + c * 64];
        float emit = emLDS[((t >> 3) & 1) * 1024 + ph * 128 + j];
        if (role == 0) {
            float Scur = sNormF[cur];                 // broadcast read
            float a0 = 0.f, a1 = 0.f, a2 = 0.f, a3 = 0.f;
            FG(0,a0) FG(1,a1) FG(2,a2) FG(3,a3) FG(4,a0) FG(5,a1) FG(6,a2) FG(7,a3)
            FG(8,a0) FG(9,a1) FG(10,a2) FG(11,a3) FG(12,a0) FG(13,a1) FG(14,a2) FG(15,a3)
            float dot = (a0 + a1) + (a2 + a3);
            dot += __shfl_xor(dot, 1);                // combine i-halves (in-wave)
            if (c == 0) {
                float anew = __logf(dot) + Sprev + emit;
                buf[(cur ^ 1) * K_ + j] = __expf(anew - Scur);
                if (j == 0) sNormF[cur ^ 1] = anew;
            }
            Sprev = Scur;
        } else {
            float m0 = NEGINF, m1 = NEGINF, m2 = NEGINF, m3 = NEGINF;
            int   a0 = 0, a1 = 0, a2 = 0, a3 = 0;
            VG(0,m0,a0) VG(1,m0,a0) VG(2,m0,a0) VG(3,m0,a0)
            VG(4,m1,a1) VG(5,m1,a1) VG(6,m1,a1) VG(7,m1,a1)
            VG(8,m2,a2) VG(9,m2,a2) VG(10,m2,a2) VG(11,m2,a2)
            VG(12,m3,a3) VG(13,m3,a3) VG(14,m3,a3) VG(15,m3,a3)
            if (m1 > m0) { m0 = m1; a0 = a1; }        // blocks ascending: strict >
            if (m3 > m2) { m2 = m3; a2 = a3; }
            if (m2 > m0) { m0 = m2; a0 = a2; }
            int arg = a0 + c * 64;
            float om = __shfl_xor(m0, 1);
            int   oa = __shfl_xor(arg, 1);
            if (om > m0 || (om == m0 && oa < arg)) { m0 = om; arg = oa; }
            if (c == 0) {
                buf[(cur ^ 1) * K_ + j] = m0 + emit;
                bp[t * K_ + j] = (unsigned char)arg;
            }
        }
        if (ph == 6) {                                // commit staged chunk to LDS
            int nc = (t >> 3) + 1;
            if (nc < T_ / 8) *(float4*)&emLDS[(nc & 1) * 1024 + tid * 4] = stv;
        }
        cur ^= 1;
        BAR();
    }

    // ---------------- epilogues ----------------
    if (role == 0) {
        float logZv = 0.f;
        if (tid < 64) {
            float s = buf[cur * K_ + tid] + buf[cur * K_ + tid + 64];
            #pragma unroll
            for (int m = 1; m < 64; m <<= 1) s += __shfl_xor(s, m);
            logZv = Sprev + __logf(s);                // lane 0 valid
        }
        if (tid == 0) {
            float sc = redS[0] + redS[1] + redS[2] + redS[3];
            ws_ll[b] = sc - logZv;
        }
    } else {
        // last tag: argmax (first-max-wins)
        if (tid < 64) {
            float m = buf[cur * K_ + tid]; int a = tid;
            float v2 = buf[cur * K_ + tid + 64];
            if (v2 > m) { m = v2; a = tid + 64; }
            #pragma unroll
            for (int s = 1; s < 64; s <<= 1) {
                float om = __shfl_xor(m, s);
                int   oa = __shfl_xor(a, s);
                if (om > m || (om == m && oa < a)) { m = om; a = oa; }
            }
            if (tid == 0) *ltag = a;
        }
        BAR();
        // backtrace (serial chain through LDS)
        if (tid == 0) {
            int tg = *ltag;
            for (int t = T_ - 1; t >= 1; --t) {
                dec[t] = (unsigned char)tg;
                if (t < len) tg = bp[t * K_ + tg];    // identity for t >= len
            }
            dec[0] = (unsigned char)tg;
        }
        BAR();
        // decoded write + accuracy (2 t's per thread)
        int good = 0;
        #pragma unroll
        for (int q = 0; q < 2; ++q) {
            int t = tid + q * 256;
            int dv = dec[t];
            out[1 + b * T_ + t] = (float)dv;
            good += (t < len && tagB[t] == dv) ? 1 : 0;
        }
        #pragma unroll
        for (int m = 1; m < 64; m <<= 1) good += __shfl_xor(good, m);
        if ((tid & 63) == 0) redI[tid >> 6] = good;
        BAR();
        if (tid == 0) ws_cnt[b] = redI[0] + redI[1] + redI[2] + redI[3];
    }
}

// loss = -mean(ll), accuracy = sum(correct)/sum(len)
__global__ void crf_final(const float* __restrict__ ws_ll,
                          const int* __restrict__ ws_cnt,
                          const int* __restrict__ lengths,
                          float* __restrict__ out)
{
    __shared__ float sll[4];
    __shared__ int scnt[4], slen[4];
    int tid = threadIdx.x;                            // blockDim == 256
    float ll = ws_ll[tid];
    int   cn = ws_cnt[tid];
    int   L  = lengths[tid];
    #pragma unroll
    for (int m = 1; m < 64; m <<= 1) {
        ll += __shfl_xor(ll, m);
        cn += __shfl_xor(cn, m);
        L  += __shfl_xor(L, m);
    }
    if ((tid & 63) == 0) { sll[tid >> 6] = ll; scnt[tid >> 6] = cn; slen[tid >> 6] = L; }
    __syncthreads();
    if (tid == 0) {
        float llS = sll[0] + sll[1] + sll[2] + sll[3];
        int   cS  = scnt[0] + scnt[1] + scnt[2] + scnt[3];
        int   LS  = slen[0] + slen[1] + slen[2] + slen[3];
        out[0] = -llS / (float)B_;
        out[1 + B_ * T_] = (float)cS / (float)LS;
    }
}

extern "C" void kernel_launch(void* const* d_in, const int* in_sizes, int n_in,
                              void* d_out, int out_size, void* d_ws, size_t ws_size,
                              hipStream_t stream) {
    const float* emissions   = (const float*)d_in[0];
    const int*   tag_ids     = (const int*)d_in[1];
    const int*   lengths     = (const int*)d_in[2];
    const float* transitions = (const float*)d_in[3];
    float* out = (float*)d_out;

    float* ws_ll  = (float*)d_ws;
    int*   ws_cnt = (int*)((char*)d_ws + B_ * sizeof(float));

    crf_main<<<2 * B_, 256, 0, stream>>>(emissions, tag_ids, lengths, transitions,
                                         out, ws_ll, ws_cnt);
    crf_final<<<1, B_, 0, stream>>>(ws_ll, ws_cnt, lengths, out);
}